// Round 2
// baseline (645.204 us; speedup 1.0000x reference)
//
#include <hip/hip_runtime.h>

#define HH 128
#define WW 128
#define HWSZ (HH * WW)
#define CC 64
#define OO 64
#define BB 4
#define NOFF 18

// ws layout (float offsets)
#define WS_OFFT   0                         // 576*18  = 10368
#define WS_DCWT   10368                     // 576*64  = 36864
#define WS_SUMS   47232                     // 64
#define WS_SUMSQ  47296                     // 64
#define WS_OFFBUF 47360                     // 4*18*16384 = 1179648
#define WS_YBUF   1227008                   // 4*64*16384 = 4194304

__global__ __launch_bounds__(256) void transpose_w_kernel(
    const float* __restrict__ off_w, const float* __restrict__ dc_w,
    float* __restrict__ offT, float* __restrict__ dcwT) {
  int tid = blockIdx.x * 256 + threadIdx.x;
  int stride = gridDim.x * 256;
  for (int i = tid; i < NOFF * CC * 9; i += stride) {
    int o = i / (CC * 9);
    int ck = i % (CC * 9);
    offT[ck * NOFF + o] = off_w[i];
  }
  for (int i = tid; i < OO * CC * 9; i += stride) {
    int o = i / (CC * 9);
    int ck = i % (CC * 9);
    dcwT[ck * OO + o] = dc_w[i];
  }
}

// Block = 256 threads = 64 pixels x 4 channel-group waves (16 ch each).
// Tree-reduce 4 partial acc[18] through LDS, wave 0 stores.
__global__ __launch_bounds__(256) void offset_conv_kernel(
    const float* __restrict__ x, const float* __restrict__ offT,
    const float* __restrict__ off_b, float* __restrict__ offbuf) {
  int cg = threadIdx.x >> 6;
  int lane = threadIdx.x & 63;
  int pix = blockIdx.x * 64 + lane;
  int b = pix >> 14;
  int hw = pix & (HWSZ - 1);
  int h = hw >> 7;
  int w = hw & 127;

  float acc[NOFF];
#pragma unroll
  for (int o = 0; o < NOFF; ++o) acc[o] = (cg == 0) ? off_b[o] : 0.0f;

  const float* xb = x + b * CC * HWSZ;
  int c0 = cg * (CC / 4);
#pragma unroll 1
  for (int c = c0; c < c0 + CC / 4; ++c) {
    const float* xp = xb + c * HWSZ;
#pragma unroll
    for (int ky = 0; ky < 3; ++ky) {
      int yy = h + ky - 1;
      bool oky = (yy >= 0) && (yy < HH);
      int cy = min(max(yy, 0), HH - 1);
#pragma unroll
      for (int kx = 0; kx < 3; ++kx) {
        int xx = w + kx - 1;
        bool ok = oky && (xx >= 0) && (xx < WW);
        int cx = min(max(xx, 0), WW - 1);
        float v = xp[cy * WW + cx];
        v = ok ? v : 0.0f;
        const float* wp = offT + (c * 9 + ky * 3 + kx) * NOFF;
#pragma unroll
        for (int o = 0; o < NOFF; ++o) acc[o] += wp[o] * v;  // wp wave-uniform -> s_load
      }
    }
  }

  // LDS tree reduction: [o][px] layout, stride 64 -> conflict-free.
  __shared__ float red[2][NOFF * 64];
  if (cg >= 2) {
    float* Lb = red[cg - 2];
#pragma unroll
    for (int o = 0; o < NOFF; ++o) Lb[o * 64 + lane] = acc[o];
  }
  __syncthreads();
  if (cg < 2) {
    float* Lb = red[cg];
#pragma unroll
    for (int o = 0; o < NOFF; ++o) acc[o] += Lb[o * 64 + lane];
  }
  __syncthreads();
  if (cg == 1) {
#pragma unroll
    for (int o = 0; o < NOFF; ++o) red[0][o * 64 + lane] = acc[o];
  }
  __syncthreads();
  if (cg == 0) {
    float* ob = offbuf + b * NOFF * HWSZ + hw;
#pragma unroll
    for (int o = 0; o < NOFF; ++o) ob[o * HWSZ] = acc[o] + red[0][o * 64 + lane];
  }
}

// Same structure: 64 px x 4 cgroup waves, acc[64], 32KB LDS tree reduce.
__global__ __launch_bounds__(256) void deform_conv_kernel(
    const float* __restrict__ x, const float* __restrict__ offbuf,
    const float* __restrict__ dcwT, const float* __restrict__ dc_b,
    float* __restrict__ ybuf) {
  int cg = threadIdx.x >> 6;
  int lane = threadIdx.x & 63;
  int pix = blockIdx.x * 64 + lane;
  int b = pix >> 14;
  int hw = pix & (HWSZ - 1);
  int h = hw >> 7;
  int w = hw & 127;

  // Bilinear meta for all 9 taps (duplicated across the 4 waves; ~180 inst, negligible).
  int base00[9], base01[9], base10[9], base11[9];
  float wt00[9], wt01[9], wt10[9], wt11[9];
  const float* ob = offbuf + b * NOFF * HWSZ + hw;
#pragma unroll
  for (int k = 0; k < 9; ++k) {
    float dy = ob[(2 * k) * HWSZ];
    float dx = ob[(2 * k + 1) * HWSZ];
    float py = (float)(h + (k / 3) - 1) + dy;
    float px = (float)(w + (k % 3) - 1) + dx;
    float fy0 = floorf(py), fx0 = floorf(px);
    float ay = py - fy0, ax = px - fx0;
    int iy0 = (int)fy0, ix0 = (int)fx0;
    int iy1 = iy0 + 1, ix1 = ix0 + 1;
    float wy0 = 1.0f - ay, wy1 = ay, wx0 = 1.0f - ax, wx1 = ax;
    if (!(iy0 >= 0 && iy0 < HH)) wy0 = 0.0f;
    if (!(iy1 >= 0 && iy1 < HH)) wy1 = 0.0f;
    if (!(ix0 >= 0 && ix0 < WW)) wx0 = 0.0f;
    if (!(ix1 >= 0 && ix1 < WW)) wx1 = 0.0f;
    int cy0 = min(max(iy0, 0), HH - 1), cy1 = min(max(iy1, 0), HH - 1);
    int cx0 = min(max(ix0, 0), WW - 1), cx1 = min(max(ix1, 0), WW - 1);
    wt00[k] = wy0 * wx0; wt01[k] = wy0 * wx1;
    wt10[k] = wy1 * wx0; wt11[k] = wy1 * wx1;
    base00[k] = cy0 * WW + cx0; base01[k] = cy0 * WW + cx1;
    base10[k] = cy1 * WW + cx0; base11[k] = cy1 * WW + cx1;
  }

  float acc[OO];
#pragma unroll
  for (int o = 0; o < OO; ++o) acc[o] = (cg == 0) ? dc_b[o] : 0.0f;

  const float* xb = x + b * CC * HWSZ;
  int c0 = cg * (CC / 4);
#pragma unroll 1
  for (int c = c0; c < c0 + CC / 4; ++c) {
    const float* xp = xb + c * HWSZ;
    const float* wbase = dcwT + c * 9 * OO;
#pragma unroll
    for (int k = 0; k < 9; ++k) {
      float s = wt00[k] * xp[base00[k]] + wt01[k] * xp[base01[k]]
              + wt10[k] * xp[base10[k]] + wt11[k] * xp[base11[k]];
      const float* wp = wbase + k * OO;
#pragma unroll
      for (int o = 0; o < OO; ++o) acc[o] += wp[o] * s;  // SGPR-operand FMA
    }
  }

  // LDS tree reduction, [o][px] stride-64 layout (conflict-free).
  __shared__ float red[2][OO * 64];
  if (cg >= 2) {
    float* Lb = red[cg - 2];
#pragma unroll
    for (int o = 0; o < OO; ++o) Lb[o * 64 + lane] = acc[o];
  }
  __syncthreads();
  if (cg < 2) {
    float* Lb = red[cg];
#pragma unroll
    for (int o = 0; o < OO; ++o) acc[o] += Lb[o * 64 + lane];
  }
  __syncthreads();
  if (cg == 1) {
#pragma unroll
    for (int o = 0; o < OO; ++o) red[0][o * 64 + lane] = acc[o];
  }
  __syncthreads();
  if (cg == 0) {
    float* yb = ybuf + b * OO * HWSZ + hw;
#pragma unroll
    for (int o = 0; o < OO; ++o) yb[o * HWSZ] = acc[o] + red[0][o * 64 + lane];
  }
}

__global__ __launch_bounds__(256) void stats_kernel(
    const float* __restrict__ ybuf, float* __restrict__ sums,
    float* __restrict__ sumsq) {
  int o = blockIdx.x & 63;
  int b = blockIdx.x >> 6;
  const float4* yp = (const float4*)(ybuf + (size_t)(b * OO + o) * HWSZ);
  float s = 0.0f, ss = 0.0f;
  for (int i = threadIdx.x; i < HWSZ / 4; i += 256) {
    float4 v = yp[i];
    s += v.x + v.y + v.z + v.w;
    ss += v.x * v.x + v.y * v.y + v.z * v.z + v.w * v.w;
  }
#pragma unroll
  for (int off = 32; off > 0; off >>= 1) {
    s += __shfl_down(s, off);
    ss += __shfl_down(ss, off);
  }
  __shared__ float ls[4], lss[4];
  int wid = threadIdx.x >> 6;
  int lane = threadIdx.x & 63;
  if (lane == 0) { ls[wid] = s; lss[wid] = ss; }
  __syncthreads();
  if (threadIdx.x == 0) {
    float ts = 0.0f, tss = 0.0f;
#pragma unroll
    for (int wv = 0; wv < 4; ++wv) { ts += ls[wv]; tss += lss[wv]; }
    atomicAdd(&sums[o], ts);
    atomicAdd(&sumsq[o], tss);
  }
}

__global__ __launch_bounds__(256) void norm_kernel(
    const float* __restrict__ ybuf, const float* __restrict__ sums,
    const float* __restrict__ sumsq, const float* __restrict__ gamma,
    const float* __restrict__ beta, float* __restrict__ out) {
  int gid = blockIdx.x * 256 + threadIdx.x;   // float4 index
  int flat = gid << 2;
  int o = (flat >> 14) & 63;
  const float invN = 1.0f / (float)(BB * HWSZ);
  float mean = sums[o] * invN;
  float var = sumsq[o] * invN - mean * mean;
  float rstd = rsqrtf(var + 1e-5f);
  float g = gamma[o] * rstd;
  float bta = beta[o] - mean * g;
  float4 v = ((const float4*)ybuf)[gid];
  float4 r;
  r.x = fmaxf(v.x * g + bta, 0.0f);
  r.y = fmaxf(v.y * g + bta, 0.0f);
  r.z = fmaxf(v.z * g + bta, 0.0f);
  r.w = fmaxf(v.w * g + bta, 0.0f);
  ((float4*)out)[gid] = r;
}

extern "C" void kernel_launch(void* const* d_in, const int* in_sizes, int n_in,
                              void* d_out, int out_size, void* d_ws, size_t ws_size,
                              hipStream_t stream) {
  const float* x     = (const float*)d_in[0];
  const float* off_w = (const float*)d_in[1];
  const float* off_b = (const float*)d_in[2];
  const float* dc_w  = (const float*)d_in[3];
  const float* dc_b  = (const float*)d_in[4];
  const float* gamma = (const float*)d_in[5];
  const float* beta  = (const float*)d_in[6];
  float* ws = (float*)d_ws;
  float* offT   = ws + WS_OFFT;
  float* dcwT   = ws + WS_DCWT;
  float* sums   = ws + WS_SUMS;
  float* sumsq  = ws + WS_SUMSQ;
  float* offbuf = ws + WS_OFFBUF;
  float* ybuf   = ws + WS_YBUF;
  float* out = (float*)d_out;

  hipMemsetAsync(sums, 0, 128 * sizeof(float), stream);  // sums + sumsq
  transpose_w_kernel<<<64, 256, 0, stream>>>(off_w, dc_w, offT, dcwT);
  offset_conv_kernel<<<BB * HWSZ / 64, 256, 0, stream>>>(x, offT, off_b, offbuf);
  deform_conv_kernel<<<BB * HWSZ / 64, 256, 0, stream>>>(x, offbuf, dcwT, dc_b, ybuf);
  stats_kernel<<<BB * OO, 256, 0, stream>>>(ybuf, sums, sumsq);
  norm_kernel<<<BB * OO * HWSZ / (4 * 256), 256, 0, stream>>>(ybuf, sums, sumsq, gamma, beta, out);
}

// Round 3
// 266.985 us; speedup vs baseline: 2.4166x; 2.4166x over previous
//
#include <hip/hip_runtime.h>

#define HH 128
#define WW 128
#define HWSZ (HH * WW)
#define CC 64
#define OO 64
#define BB 4
#define NOFF 18
#define KK 576          // C*9
#define K2 288          // KK/2 (bf16 pairs)

// ws layout (float offsets)
#define WS_OFFT   0                         // 576*18  = 10368 floats
#define WS_BG     10368                     // 288*64  = 18432 dwords (bf16-pair weights)
#define WS_SUMS   47232                     // 64
#define WS_SUMSQ  47296                     // 64
#define WS_OFFBUF 47360                     // 4*18*16384 = 1179648
#define WS_YBUF   1227008                   // 4*64*16384 = 4194304

typedef __attribute__((ext_vector_type(8))) short short8;
typedef __attribute__((ext_vector_type(4))) int int4v;
typedef __attribute__((ext_vector_type(4))) float f32x4;

__device__ inline unsigned bf16rne(float f) {
  unsigned u = __float_as_uint(f);
  u += 0x7fff + ((u >> 16) & 1);   // round-to-nearest-even (finite inputs)
  return u >> 16;
}

// offT: [64*9][18] fp32 for offset conv; Bg: [288][64] dwords, each = bf16 pair
// (k=2*k2 low half, k=2*k2+1 high half) of dc_w[o][k], k = c*9+ky*3+kx.
__global__ __launch_bounds__(256) void prep_w_kernel(
    const float* __restrict__ off_w, const float* __restrict__ dc_w,
    float* __restrict__ offT, int* __restrict__ Bg) {
  int tid = blockIdx.x * 256 + threadIdx.x;
  int stride = gridDim.x * 256;
  for (int i = tid; i < NOFF * CC * 9; i += stride) {
    int o = i / (CC * 9);
    int ck = i % (CC * 9);
    offT[ck * NOFF + o] = off_w[i];
  }
  for (int i = tid; i < K2 * OO; i += stride) {
    int k2 = i >> 6;
    int o = i & 63;
    unsigned lo = bf16rne(dc_w[o * KK + 2 * k2]);
    unsigned hi = bf16rne(dc_w[o * KK + 2 * k2 + 1]);
    Bg[i] = (int)(lo | (hi << 16));
  }
}

// Round-1 offset conv: 1 thread = 1 pixel, 18 accumulators, wave-uniform weights.
__global__ __launch_bounds__(256) void offset_conv_kernel(
    const float* __restrict__ x, const float* __restrict__ offT,
    const float* __restrict__ off_b, float* __restrict__ offbuf) {
  int idx = blockIdx.x * 256 + threadIdx.x;
  int b = idx >> 14;
  int hw = idx & (HWSZ - 1);
  int h = hw >> 7;
  int w = hw & 127;

  float acc[NOFF];
#pragma unroll
  for (int o = 0; o < NOFF; ++o) acc[o] = off_b[o];

  const float* xb = x + b * CC * HWSZ;
#pragma unroll 1
  for (int c = 0; c < CC; ++c) {
    const float* xp = xb + c * HWSZ;
#pragma unroll
    for (int ky = 0; ky < 3; ++ky) {
      int yy = h + ky - 1;
      bool oky = (yy >= 0) && (yy < HH);
      int cy = min(max(yy, 0), HH - 1);
#pragma unroll
      for (int kx = 0; kx < 3; ++kx) {
        int xx = w + kx - 1;
        bool ok = oky && (xx >= 0) && (xx < WW);
        int cx = min(max(xx, 0), WW - 1);
        float v = xp[cy * WW + cx];
        v = ok ? v : 0.0f;
        const float* wp = offT + (c * 9 + ky * 3 + kx) * NOFF;
#pragma unroll
        for (int o = 0; o < NOFF; ++o) acc[o] += wp[o] * v;
      }
    }
  }
  float* ob = offbuf + b * NOFF * HWSZ + hw;
#pragma unroll
  for (int o = 0; o < NOFF; ++o) ob[o * HWSZ] = acc[o];
}

// Deform conv as im2col + MFMA GEMM.
// Block = 64 pixels (one half-row) x 256 threads (4 waves).
// Phase 1: wave cg gathers channels [16cg,16cg+16) x 9 taps for px=lane,
//          packs bf16 pairs into A_lds[k2][px] (dword, conflict-free).
// Phase 2: wave cg computes m-tile (px 16cg..16cg+16) x all 64 O via
//          18 k-steps of 4x v_mfma_f32_16x16x32_bf16; B from global bf16-pair
//          layout (L2-resident, vector loads, no scalar-load chains).
__global__ __launch_bounds__(256) void deform_mfma_kernel(
    const float* __restrict__ x, const float* __restrict__ offbuf,
    const int* __restrict__ Bg, const float* __restrict__ dc_b,
    float* __restrict__ ybuf) {
  __shared__ int A_lds[K2 * 64];   // 73728 B

  int cg = threadIdx.x >> 6;
  int lane = threadIdx.x & 63;
  int b = blockIdx.x >> 8;
  int rem = blockIdx.x & 255;
  int h = rem >> 1;
  int w0 = (rem & 1) * 64;
  int hw0 = h * WW + w0;
  int hw = hw0 + lane;           // this lane's pixel
  int w = w0 + lane;

  // ---- bilinear meta for 9 taps at px = lane ----
  int base00[9], base01[9], base10[9], base11[9];
  float wt00[9], wt01[9], wt10[9], wt11[9];
  const float* ob = offbuf + b * NOFF * HWSZ + hw;
#pragma unroll
  for (int k = 0; k < 9; ++k) {
    float dy = ob[(2 * k) * HWSZ];
    float dx = ob[(2 * k + 1) * HWSZ];
    float py = (float)(h + (k / 3) - 1) + dy;
    float px = (float)(w + (k % 3) - 1) + dx;
    float fy0 = floorf(py), fx0 = floorf(px);
    float ay = py - fy0, ax = px - fx0;
    int iy0 = (int)fy0, ix0 = (int)fx0;
    int iy1 = iy0 + 1, ix1 = ix0 + 1;
    float wy0 = 1.0f - ay, wy1 = ay, wx0 = 1.0f - ax, wx1 = ax;
    if (!(iy0 >= 0 && iy0 < HH)) wy0 = 0.0f;
    if (!(iy1 >= 0 && iy1 < HH)) wy1 = 0.0f;
    if (!(ix0 >= 0 && ix0 < WW)) wx0 = 0.0f;
    if (!(ix1 >= 0 && ix1 < WW)) wx1 = 0.0f;
    int cy0 = min(max(iy0, 0), HH - 1), cy1 = min(max(iy1, 0), HH - 1);
    int cx0 = min(max(ix0, 0), WW - 1), cx1 = min(max(ix1, 0), WW - 1);
    wt00[k] = wy0 * wx0; wt01[k] = wy0 * wx1;
    wt10[k] = wy1 * wx0; wt11[k] = wy1 * wx1;
    base00[k] = cy0 * WW + cx0; base01[k] = cy0 * WW + cx1;
    base10[k] = cy1 * WW + cx0; base11[k] = cy1 * WW + cx1;
  }

  // ---- phase 1: gather + pack; 2 channels (18 samples -> 9 dwords) per iter ----
  const float* xb = x + (b * CC + cg * 16) * HWSZ;
#pragma unroll 1
  for (int c16 = 0; c16 < 16; c16 += 2) {
    const float* xp0 = xb + c16 * HWSZ;
    const float* xp1 = xp0 + HWSZ;
    float s2[18];
#pragma unroll
    for (int t = 0; t < 9; ++t) {
      s2[t] = wt00[t] * xp0[base00[t]] + wt01[t] * xp0[base01[t]]
            + wt10[t] * xp0[base10[t]] + wt11[t] * xp0[base11[t]];
      s2[9 + t] = wt00[t] * xp1[base00[t]] + wt01[t] * xp1[base01[t]]
                + wt10[t] * xp1[base10[t]] + wt11[t] * xp1[base11[t]];
    }
    int k2base = cg * 72 + (c16 * 9) / 2;   // c16 even -> integer
#pragma unroll
    for (int j = 0; j < 9; ++j) {
      unsigned pk = bf16rne(s2[2 * j]) | (bf16rne(s2[2 * j + 1]) << 16);
      A_lds[(k2base + j) * 64 + lane] = (int)pk;
    }
  }
  __syncthreads();

  // ---- phase 2: MFMA ----
  int n16 = lane & 15;
  int q = lane >> 4;
  int mrow = cg * 16 + n16;                 // A-frag row (pixel) for this lane
  const int* Bg_lane = Bg + q * 256 + n16;  // (4q)*64 + n16
  f32x4 acc[4] = {f32x4{0,0,0,0}, f32x4{0,0,0,0}, f32x4{0,0,0,0}, f32x4{0,0,0,0}};
#pragma unroll 1
  for (int kk = 0; kk < 18; ++kk) {
    int abase = (kk * 16 + q * 4) * 64 + mrow;
    int4v av;
    av.x = A_lds[abase];
    av.y = A_lds[abase + 64];
    av.z = A_lds[abase + 128];
    av.w = A_lds[abase + 192];
    short8 af = __builtin_bit_cast(short8, av);
    const int* bp = Bg_lane + kk * 1024;
#pragma unroll
    for (int nt = 0; nt < 4; ++nt) {
      int4v bv;
      bv.x = bp[nt * 16];
      bv.y = bp[nt * 16 + 64];
      bv.z = bp[nt * 16 + 128];
      bv.w = bp[nt * 16 + 192];
      short8 bfr = __builtin_bit_cast(short8, bv);
      acc[nt] = __builtin_amdgcn_mfma_f32_16x16x32_bf16(af, bfr, acc[nt], 0, 0, 0);
    }
  }

  // ---- epilogue: D[row=q*4+reg][col=n16] per m89-verified C/D mapping ----
#pragma unroll
  for (int nt = 0; nt < 4; ++nt) {
    int o = nt * 16 + n16;
    float bv = dc_b[o];
    float* yb = ybuf + (size_t)(b * OO + o) * HWSZ + hw0 + cg * 16 + q * 4;
#pragma unroll
    for (int r = 0; r < 4; ++r) yb[r] = acc[nt][r] + bv;
  }
}

__global__ __launch_bounds__(256) void stats_kernel(
    const float* __restrict__ ybuf, float* __restrict__ sums,
    float* __restrict__ sumsq) {
  int o = blockIdx.x & 63;
  int b = blockIdx.x >> 6;
  const float4* yp = (const float4*)(ybuf + (size_t)(b * OO + o) * HWSZ);
  float s = 0.0f, ss = 0.0f;
  for (int i = threadIdx.x; i < HWSZ / 4; i += 256) {
    float4 v = yp[i];
    s += v.x + v.y + v.z + v.w;
    ss += v.x * v.x + v.y * v.y + v.z * v.z + v.w * v.w;
  }
#pragma unroll
  for (int off = 32; off > 0; off >>= 1) {
    s += __shfl_down(s, off);
    ss += __shfl_down(ss, off);
  }
  __shared__ float ls[4], lss[4];
  int wid = threadIdx.x >> 6;
  int lane = threadIdx.x & 63;
  if (lane == 0) { ls[wid] = s; lss[wid] = ss; }
  __syncthreads();
  if (threadIdx.x == 0) {
    float ts = 0.0f, tss = 0.0f;
#pragma unroll
    for (int wv = 0; wv < 4; ++wv) { ts += ls[wv]; tss += lss[wv]; }
    atomicAdd(&sums[o], ts);
    atomicAdd(&sumsq[o], tss);
  }
}

__global__ __launch_bounds__(256) void norm_kernel(
    const float* __restrict__ ybuf, const float* __restrict__ sums,
    const float* __restrict__ sumsq, const float* __restrict__ gamma,
    const float* __restrict__ beta, float* __restrict__ out) {
  int gid = blockIdx.x * 256 + threadIdx.x;   // float4 index
  int flat = gid << 2;
  int o = (flat >> 14) & 63;
  const float invN = 1.0f / (float)(BB * HWSZ);
  float mean = sums[o] * invN;
  float var = sumsq[o] * invN - mean * mean;
  float rstd = rsqrtf(var + 1e-5f);
  float g = gamma[o] * rstd;
  float bta = beta[o] - mean * g;
  float4 v = ((const float4*)ybuf)[gid];
  float4 r;
  r.x = fmaxf(v.x * g + bta, 0.0f);
  r.y = fmaxf(v.y * g + bta, 0.0f);
  r.z = fmaxf(v.z * g + bta, 0.0f);
  r.w = fmaxf(v.w * g + bta, 0.0f);
  ((float4*)out)[gid] = r;
}

extern "C" void kernel_launch(void* const* d_in, const int* in_sizes, int n_in,
                              void* d_out, int out_size, void* d_ws, size_t ws_size,
                              hipStream_t stream) {
  const float* x     = (const float*)d_in[0];
  const float* off_w = (const float*)d_in[1];
  const float* off_b = (const float*)d_in[2];
  const float* dc_w  = (const float*)d_in[3];
  const float* dc_b  = (const float*)d_in[4];
  const float* gamma = (const float*)d_in[5];
  const float* beta  = (const float*)d_in[6];
  float* ws = (float*)d_ws;
  float* offT   = ws + WS_OFFT;
  int*   Bg     = (int*)(ws + WS_BG);
  float* sums   = ws + WS_SUMS;
  float* sumsq  = ws + WS_SUMSQ;
  float* offbuf = ws + WS_OFFBUF;
  float* ybuf   = ws + WS_YBUF;
  float* out = (float*)d_out;

  hipMemsetAsync(sums, 0, 128 * sizeof(float), stream);  // sums + sumsq
  prep_w_kernel<<<64, 256, 0, stream>>>(off_w, dc_w, offT, Bg);
  offset_conv_kernel<<<BB * HWSZ / 256, 256, 0, stream>>>(x, offT, off_b, offbuf);
  deform_mfma_kernel<<<BB * HWSZ / 64, 256, 0, stream>>>(x, offbuf, Bg, dc_b, ybuf);
  stats_kernel<<<BB * OO, 256, 0, stream>>>(ybuf, sums, sumsq);
  norm_kernel<<<BB * OO * HWSZ / (4 * 256), 256, 0, stream>>>(ybuf, sums, sumsq, gamma, beta, out);
}